// Round 3
// baseline (202.976 us; speedup 1.0000x reference)
//
#include <hip/hip_runtime.h>

typedef _Float16 f16;
typedef _Float16 f16x8 __attribute__((ext_vector_type(8)));
typedef float f32x4 __attribute__((ext_vector_type(4)));

#define NN 8192
#define GG 128
#define NSPLIT 8

typedef __attribute__((address_space(3))) unsigned as3u;
typedef const __attribute__((address_space(1))) unsigned as1u;

__device__ __forceinline__ void gload16(const f16* g, f16* l) {
  __builtin_amdgcn_global_load_lds((as1u*)g, (as3u*)l, 16, 0, 0);
}
__device__ __forceinline__ void gload4(const f16* g, f16* l) {
  __builtin_amdgcn_global_load_lds((as1u*)g, (as3u*)l, 4, 0, 0);
}

#define SBAR() asm volatile("s_barrier" ::: "memory")
#define WAITV(N) asm volatile("s_waitcnt vmcnt(" #N ")" ::: "memory")
#define WAITL0() asm volatile("s_waitcnt lgkmcnt(0)" ::: "memory")

__device__ __forceinline__ f16x8 ldcvt8(const float* p) {
  f32x4 a = *(const f32x4*)p;
  f32x4 b = *(const f32x4*)(p + 4);
  f16x8 r;
  r[0] = (f16)a[0]; r[1] = (f16)a[1]; r[2] = (f16)a[2]; r[3] = (f16)a[3];
  r[4] = (f16)b[0]; r[5] = (f16)b[1]; r[6] = (f16)b[2]; r[7] = (f16)b[3];
  return r;
}

// ---------------- wz[k] = W_k @ z0 for k=0..3 (proven) ----------------
__global__ __launch_bounds__(512, 2) void k_wz(const float* __restrict__ wt,
                                               const float* __restrict__ x,
                                               f16* __restrict__ wz) {
  const int tid = (int)threadIdx.x;
  const int w = tid >> 6, l = tid & 63, lo = l & 15, hi = l >> 4;
  const int rg = w >> 1, cg = w & 1;
  const int ktap = (int)blockIdx.y;
  const int n0 = (int)blockIdx.x * 32;
  const int rowA = rg * 32;
  const float* wA0 = wt + (size_t)(rowA + lo) * 512 + (size_t)ktap * 128 + 8 * hi;
  const float* wA1 = wA0 + (size_t)16 * 512;
  const float* xB = x + (size_t)(n0 + 16 * cg + lo) * GG + 8 * hi;
  f32x4 acc[2] = {};
#pragma unroll
  for (int s = 0; s < 4; ++s) {
    f16x8 a0 = ldcvt8(wA0 + s * 32);
    f16x8 a1 = ldcvt8(wA1 + s * 32);
    f16x8 b = ldcvt8(xB + s * 32);
    acc[0] = __builtin_amdgcn_mfma_f32_16x16x32_f16(a0, b, acc[0], 0, 0, 0);
    acc[1] = __builtin_amdgcn_mfma_f32_16x16x32_f16(a1, b, acc[1], 0, 0, 0);
  }
  f16* out = wz + (size_t)ktap * (GG * NN);
#pragma unroll
  for (int fm = 0; fm < 2; ++fm)
#pragma unroll
    for (int rr = 0; rr < 4; ++rr) {
      int row = rowA + 16 * fm + 4 * hi + rr;
      out[(size_t)row * NN + n0 + 16 * cg + lo] = (f16)acc[fm][rr];
    }
}

// ---------------- fused tap1: stream S fp32 -> cvt f16 -> {LDS B (swz), Sbt} + MFMA ----
// Schedule proven (rounds 1-2). Sbt global store RE-LAID for k_tapK consumers:
// panel p = n/32 (256 panels x 512 KB, contiguous per-consumer stream), chunk
// c = k/64 (4 KB), within-chunk f16 offset = ((n'<<6)+kk) ^ ((n'&7)<<3).
// Each 128-B line (one n', 64 kk) fully written by 8 threads -> write-combining OK.
__global__ __launch_bounds__(256, 2) void k_tap1F(const f16* __restrict__ A,
                                                  const float* __restrict__ S,
                                                  f16* __restrict__ Sbt,
                                                  f16* __restrict__ Part) {
  __shared__ __align__(16) f16 sm[2 * 16384];  // 2 bufs x (A 16KB + B 16KB)

  const int tid = (int)threadIdx.x;
  const int w = tid >> 6, l = tid & 63, lo = l & 15, hi = l >> 4;
  const int wm = w >> 1, wn = w & 1;
  const int kg = tid >> 5, cg = tid & 31, ch = kg >> 2, khi = kg & 3;
  const int nb = (int)blockIdx.x, ks = (int)blockIdx.y;
  const int n0 = nb * 128;
  const int k0 = ks * 1024;

  const int r1 = tid >> 2, q = tid & 3;
  const f16* aS1 = A + (size_t)r1 * NN + k0 + 8 * (q ^ (r1 & 3));
  const f16* aS2 = A + (size_t)(64 + r1) * NN + k0 + 8 * (q ^ (r1 & 3));
  const float* Sb = S + (size_t)(k0 + 8 * kg) * NN + n0 + 4 * cg;
  // new layout: base panel 4*nb, chunk base 16*ks (panel = 32n x 8192k = 262144 f16)
  f16* panel = Sbt + (size_t)(4 * nb) * 262144 + (size_t)(16 * ks) * 2048;

  f32x4 rgA[8], rgB[8];
  f32x4 acc[4][4] = {};

#define ISSUE_R(T, RG)                                                          \
  do {                                                                          \
    const float* s_ = Sb + (size_t)(64 * (T)) * NN;                             \
    _Pragma("unroll") for (int j_ = 0; j_ < 8; ++j_)                            \
        RG[j_] = __builtin_nontemporal_load((const f32x4*)(s_ + (size_t)j_ * NN)); \
  } while (0)

#define ISSUE_G(T)                                                              \
  do {                                                                          \
    f16* bA_ = sm + ((T)&1) * 16384;                                            \
    gload16(aS1 + 64 * (T), bA_ + tid * 8);                                     \
    gload16(aS2 + 64 * (T), bA_ + 2048 + tid * 8);                              \
    gload16(aS1 + 64 * (T) + 32, bA_ + 4096 + tid * 8);                         \
    gload16(aS2 + 64 * (T) + 32, bA_ + 4096 + 2048 + tid * 8);                  \
  } while (0)

#define CVT_W(T, RG)                                                            \
  do {                                                                          \
    f16* bB_ = sm + ((T)&1) * 16384 + 8192 + ch * 4096;                         \
    _Pragma("unroll") for (int i_ = 0; i_ < 4; ++i_) {                          \
      f16x8 h_;                                                                 \
      _Pragma("unroll") for (int j_ = 0; j_ < 8; ++j_) h_[j_] = (f16)RG[j_][i_]; \
      const int c_ = 4 * cg + i_;                                               \
      const int u_ = ((c_ >> 4) << 6) + (khi << 4) + (c_ & 15);                 \
      *(f16x8*)(bB_ + (size_t)(u_ ^ (cg >> 2)) * 8) = h_;                       \
      const int np_ = c_ >> 5, nq_ = c_ & 31;                                   \
      *(f16x8*)(panel + (size_t)np_ * 262144 + (size_t)(T) * 2048 +             \
                ((((nq_) << 6) + (kg << 3)) ^ ((nq_ & 7) << 3))) = h_;          \
    }                                                                           \
  } while (0)

  auto compute2 = [&](int par) {  // one 64-k pair = 2 chunks x 16 MFMA
    const f16* base = sm + par * 16384;
#pragma unroll
    for (int cc = 0; cc < 2; ++cc) {
      const f16* Ab = base + cc * 4096;
      const f16* Bb = base + 8192 + cc * 4096;
      f16x8 af[4], bf[4];
#pragma unroll
      for (int fm = 0; fm < 4; ++fm) {
        const int row = 64 * wm + 16 * fm + lo;
        af[fm] = *(const f16x8*)(Ab + row * 32 + 8 * (hi ^ (row & 3)));
      }
#pragma unroll
      for (int fn = 0; fn < 4; ++fn) {
        const int uu = ((wn * 4 + fn) << 6) + (hi << 4) + lo;
        bf[fn] = *(const f16x8*)(Bb + (size_t)(uu ^ (wn * 4 + fn)) * 8);
      }
      WAITL0();
      __builtin_amdgcn_sched_barrier(0);
      __builtin_amdgcn_s_setprio(1);
#pragma unroll
      for (int fm = 0; fm < 4; ++fm)
#pragma unroll
        for (int fn = 0; fn < 4; ++fn)
          acc[fm][fn] = __builtin_amdgcn_mfma_f32_16x16x32_f16(af[fm], bf[fn], acc[fm][fn], 0, 0, 0);
      __builtin_amdgcn_s_setprio(0);
    }
  };

  ISSUE_R(0, rgA);
  ISSUE_R(1, rgB);
  ISSUE_G(0);
  __builtin_amdgcn_sched_barrier(0);
  WAITV(12);
  __builtin_amdgcn_sched_barrier(0);
  CVT_W(0, rgA);
  __builtin_amdgcn_sched_barrier(0);

  for (int tt = 0; tt < 7; ++tt) {
    const int t0 = 2 * tt;
    ISSUE_R(t0 + 2, rgA);
    ISSUE_G(t0 + 1);
    __builtin_amdgcn_sched_barrier(0);
    WAITV(20);  // R8(p t0+1) done: after it G4+S4+R8+G4 = 20
    __builtin_amdgcn_sched_barrier(0);
    CVT_W(t0 + 1, rgB);
    __builtin_amdgcn_sched_barrier(0);
    WAITV(20);  // G4(p t0) done: after it S4+R8+G4+S4 = 20
    WAITL0();
    SBAR();
    compute2(0);
    SBAR();
    ISSUE_R(t0 + 3, rgB);
    ISSUE_G(t0 + 2);
    __builtin_amdgcn_sched_barrier(0);
    WAITV(20);
    __builtin_amdgcn_sched_barrier(0);
    CVT_W(t0 + 2, rgA);
    __builtin_amdgcn_sched_barrier(0);
    WAITV(20);
    WAITL0();
    SBAR();
    compute2(1);
    SBAR();
  }
  ISSUE_G(15);
  __builtin_amdgcn_sched_barrier(0);
  WAITV(12);
  __builtin_amdgcn_sched_barrier(0);
  CVT_W(15, rgB);
  __builtin_amdgcn_sched_barrier(0);
  WAITV(12);
  WAITL0();
  SBAR();
  compute2(0);
  SBAR();
  WAITV(4);
  __builtin_amdgcn_sched_barrier(0);
  SBAR();
  compute2(1);

#undef ISSUE_R
#undef ISSUE_G
#undef CVT_W

  f16* P = Part + (size_t)blockIdx.y * (GG * NN);
#pragma unroll
  for (int fm = 0; fm < 4; ++fm)
#pragma unroll
    for (int fn = 0; fn < 4; ++fn) {
      const int n = n0 + 64 * wn + 16 * fn + lo;
#pragma unroll
      for (int rr = 0; rr < 4; ++rr) {
        const int g = 64 * wm + 16 * fm + 4 * hi + rr;
        P[(size_t)g * NN + n] = (f16)acc[fm][fn][rr];
      }
    }
}

// ---------------- full-K tap (taps 2/3): no Part, no combine ----------------
// 256 blocks (1/CU), 512 threads (8 waves). Block owns out[128 g][32 n], K=8192.
// A (t, chunk-swizzled): [128 chunks][128 g][64 kk] ^swz, 16 KB/chunk, L2-resident.
// B (Sbt panel): [256 panels][128 chunks][32 n'][64 kk] ^swz, 4 KB/chunk, HBM stream.
// Depth-4 / 5-buffer pipeline; 4 gloads/stage -> steady WAITV(16).
template <int FINAL>
__global__ __launch_bounds__(512, 2) void k_tapK(
    const f16* __restrict__ A, const f16* __restrict__ Bt,
    const f16* __restrict__ wzk, const float* __restrict__ bs,
    f16* __restrict__ tn, float* __restrict__ y) {
  __shared__ __align__(16) f16 sm[5 * 10240];  // 100 KB: 5 x (A 8192 + B 2048 f16)

  const int tid = (int)threadIdx.x;
  const int w = tid >> 6, l = tid & 63, lo = l & 15, hi = l >> 4;
  const int n0 = (int)blockIdx.x * 32;
  const f16* Bp = Bt + (size_t)blockIdx.x * 262144;

  f32x4 acc[2] = {};

  auto stage = [&](int t, int buf) {
    f16* bufA = sm + buf * 10240;
    f16* bufB = bufA + 8192;
    const f16* Ag = A + (size_t)t * 8192;
    const f16* Bg = Bp + (size_t)t * 2048;
    gload16(Ag + tid * 8, bufA + tid * 8);
    gload16(Ag + 4096 + tid * 8, bufA + 4096 + tid * 8);
    gload4(Bg + tid * 2, bufB + tid * 2);
    gload4(Bg + 1024 + tid * 2, bufB + 1024 + tid * 2);
  };

  auto compute = [&](int buf) {
    const f16* bufA = sm + buf * 10240;
    const f16* bufB = bufA + 8192;
    f16x8 af[2], bf[2][2];
    const int g = 16 * w + lo;
#pragma unroll
    for (int s = 0; s < 2; ++s) {
      af[s] = *(const f16x8*)(bufA + (((g << 6) + (s << 5) + (hi << 3)) ^ ((lo & 7) << 3)));
#pragma unroll
      for (int fn = 0; fn < 2; ++fn) {
        const int nn = 16 * fn + lo;
        bf[s][fn] = *(const f16x8*)(bufB + (((nn << 6) + (s << 5) + (hi << 3)) ^ ((nn & 7) << 3)));
      }
    }
    WAITL0();
    __builtin_amdgcn_sched_barrier(0);
    __builtin_amdgcn_s_setprio(1);
#pragma unroll
    for (int s = 0; s < 2; ++s)
#pragma unroll
      for (int fn = 0; fn < 2; ++fn)
        acc[fn] = __builtin_amdgcn_mfma_f32_16x16x32_f16(af[s], bf[s][fn], acc[fn], 0, 0, 0);
    __builtin_amdgcn_s_setprio(0);
  };

  stage(0, 0); stage(1, 1); stage(2, 2); stage(3, 3);
  int cb = 0, ib = 4;
  for (int t = 0; t < 124; ++t) {
    stage(t + 4, ib);
    __builtin_amdgcn_sched_barrier(0);
    WAITV(16);  // 5 stages x4 in flight -> retire stage t
    SBAR();
    compute(cb);
    SBAR();
    cb = (cb == 4) ? 0 : cb + 1;
    ib = (ib == 4) ? 0 : ib + 1;
  }
  WAITV(12); SBAR(); compute(cb); SBAR(); cb = (cb == 4) ? 0 : cb + 1;
  WAITV(8);  SBAR(); compute(cb); SBAR(); cb = (cb == 4) ? 0 : cb + 1;
  WAITV(4);  SBAR(); compute(cb); SBAR(); cb = (cb == 4) ? 0 : cb + 1;
  WAITV(0);  SBAR(); compute(cb);

  const int g0 = 16 * w + 4 * hi;
  if (FINAL) {
#pragma unroll
    for (int fn = 0; fn < 2; ++fn) {
      const int n = n0 + 16 * fn + lo;
#pragma unroll
      for (int rr = 0; rr < 4; ++rr) {
        const int gg = g0 + rr;
        y[(size_t)gg * NN + n] = acc[fn][rr] + (float)wzk[(size_t)gg * NN + n] + bs[gg];
      }
    }
  } else {
#pragma unroll
    for (int fn = 0; fn < 2; ++fn) {
      const int n = n0 + 16 * fn + lo;
      const int c = n >> 6, kk = n & 63;
#pragma unroll
      for (int rr = 0; rr < 4; ++rr) {
        const int gg = g0 + rr;
        tn[(size_t)c * 8192 + (((gg << 6) + kk) ^ ((gg & 7) << 3))] =
            (f16)(acc[fn][rr] + (float)wzk[(size_t)gg * NN + n]);
      }
    }
  }
}

// ---------------- combine (tap1 only): Part-sum + wz2 -> chunk-swizzled ta ----
__global__ void k_combineC(const f16* __restrict__ Part, const f16* __restrict__ wz2,
                           f16* __restrict__ ta) {
  const int idx = (int)blockIdx.x * 512 + (int)threadIdx.x;  // 8 elems each
  const size_t off = (size_t)idx * 8;
  f16x8 wv = *(const f16x8*)(wz2 + off);
  float s[8];
#pragma unroll
  for (int j = 0; j < 8; ++j) s[j] = (float)wv[j];
#pragma unroll
  for (int sp = 0; sp < NSPLIT; ++sp) {
    f16x8 p = __builtin_nontemporal_load((const f16x8*)(Part + (size_t)sp * (GG * NN) + off));
#pragma unroll
    for (int j = 0; j < 8; ++j) s[j] += (float)p[j];
  }
  f16x8 o;
#pragma unroll
  for (int j = 0; j < 8; ++j) o[j] = (f16)s[j];
  const int g = (int)(off >> 13);
  const int nl = (int)(off & 8191);
  const int c = nl >> 6, kk0 = nl & 63;
  *(f16x8*)(ta + (size_t)c * 8192 + (((g << 6) + kk0) ^ ((g & 7) << 3))) = o;
}

extern "C" void kernel_launch(void* const* d_in, const int* in_sizes, int n_in, void* d_out,
                              int out_size, void* d_ws, size_t ws_size, hipStream_t stream) {
  const float* x = (const float*)d_in[0];   // [8192][128]
  const float* S = (const float*)d_in[1];   // [8192][8192] fp32
  const float* wt = (const float*)d_in[2];  // [128][1][4][128]
  const float* bs = (const float*)d_in[3];  // [128]
  float* y = (float*)d_out;                 // [128][8192] fp32
  char* ws = (char*)d_ws;

  const size_t offSbt = 0;                               // Sbt panels f16: 134.2 MB
  const size_t offWz = offSbt + (size_t)NN * NN * 2;     // wz[4][128][8192] f16: 8 MB
  const size_t offTa = offWz + (size_t)4 * GG * NN * 2;  // t buf A (chunked): 2 MB
  const size_t offTb = offTa + (size_t)GG * NN * 2;      // t buf B (chunked): 2 MB
  const size_t offP = offTb + (size_t)GG * NN * 2;       // Part f16 [8][128][8192]: 16.8 MB
  const size_t need = offP + (size_t)NSPLIT * GG * NN * 2;
  if (ws_size < need) return;

  f16* Sbt = (f16*)(ws + offSbt);
  f16* wz = (f16*)(ws + offWz);
  f16* ta = (f16*)(ws + offTa);
  f16* tb = (f16*)(ws + offTb);
  f16* Part = (f16*)(ws + offP);

  // Horner: t3=wz3; tap1(split-K)+combine -> ta=t2; tapK -> tb=t1; tapK -> y.
  k_wz<<<dim3(256, 4), 512, 0, stream>>>(wt, x, wz);
  k_tap1F<<<dim3(64, NSPLIT), 256, 0, stream>>>(wz + (size_t)3 * GG * NN, S, Sbt, Part);
  k_combineC<<<dim3(256), 512, 0, stream>>>(Part, wz + (size_t)2 * GG * NN, ta);
  k_tapK<0><<<dim3(256), 512, 0, stream>>>(ta, Sbt, wz + (size_t)1 * GG * NN, nullptr, tb, nullptr);
  k_tapK<1><<<dim3(256), 512, 0, stream>>>(tb, Sbt, wz, bs, nullptr, y);
}

// Round 4
// 172.244 us; speedup vs baseline: 1.1784x; 1.1784x over previous
//
#include <hip/hip_runtime.h>

typedef _Float16 f16;
typedef _Float16 f16x8 __attribute__((ext_vector_type(8)));
typedef float f32x4 __attribute__((ext_vector_type(4)));

#define NN 8192
#define GG 128
#define NSPLIT 8

typedef __attribute__((address_space(3))) unsigned as3u;
typedef const __attribute__((address_space(1))) unsigned as1u;

__device__ __forceinline__ void gload16(const f16* g, f16* l) {
  __builtin_amdgcn_global_load_lds((as1u*)g, (as3u*)l, 16, 0, 0);
}

#define SBAR() asm volatile("s_barrier" ::: "memory")
#define WAITV(N) asm volatile("s_waitcnt vmcnt(" #N ")" ::: "memory")
#define WAITL0() asm volatile("s_waitcnt lgkmcnt(0)" ::: "memory")

__device__ __forceinline__ f16x8 ldcvt8(const float* p) {
  f32x4 a = *(const f32x4*)p;
  f32x4 b = *(const f32x4*)(p + 4);
  f16x8 r;
  r[0] = (f16)a[0]; r[1] = (f16)a[1]; r[2] = (f16)a[2]; r[3] = (f16)a[3];
  r[4] = (f16)b[0]; r[5] = (f16)b[1]; r[6] = (f16)b[2]; r[7] = (f16)b[3];
  return r;
}

// ---------------- wz[k] = W_k @ z0 for k=0..3 (proven) ----------------
__global__ __launch_bounds__(512, 2) void k_wz(const float* __restrict__ wt,
                                               const float* __restrict__ x,
                                               f16* __restrict__ wz) {
  const int tid = (int)threadIdx.x;
  const int w = tid >> 6, l = tid & 63, lo = l & 15, hi = l >> 4;
  const int rg = w >> 1, cg = w & 1;
  const int ktap = (int)blockIdx.y;
  const int n0 = (int)blockIdx.x * 32;
  const int rowA = rg * 32;
  const float* wA0 = wt + (size_t)(rowA + lo) * 512 + (size_t)ktap * 128 + 8 * hi;
  const float* wA1 = wA0 + (size_t)16 * 512;
  const float* xB = x + (size_t)(n0 + 16 * cg + lo) * GG + 8 * hi;
  f32x4 acc[2] = {};
#pragma unroll
  for (int s = 0; s < 4; ++s) {
    f16x8 a0 = ldcvt8(wA0 + s * 32);
    f16x8 a1 = ldcvt8(wA1 + s * 32);
    f16x8 b = ldcvt8(xB + s * 32);
    acc[0] = __builtin_amdgcn_mfma_f32_16x16x32_f16(a0, b, acc[0], 0, 0, 0);
    acc[1] = __builtin_amdgcn_mfma_f32_16x16x32_f16(a1, b, acc[1], 0, 0, 0);
  }
  f16* out = wz + (size_t)ktap * (GG * NN);
#pragma unroll
  for (int fm = 0; fm < 2; ++fm)
#pragma unroll
    for (int rr = 0; rr < 4; ++rr) {
      int row = rowA + 16 * fm + 4 * hi + rr;
      out[(size_t)row * NN + n0 + 16 * cg + lo] = (f16)acc[fm][rr];
    }
}

// ---------------- fused tap1: stream S fp32 -> cvt f16 -> {LDS B (swz), Sbt} + MFMA ----
// R2 version verbatim (proven schedule; Sbt stores in the R0 tiled layout with
// 256-B-contiguous store groups -- R3's scattered layout regressed).
__global__ __launch_bounds__(256, 2) void k_tap1F(const f16* __restrict__ A,
                                                  const float* __restrict__ S,
                                                  f16* __restrict__ Sbt,
                                                  f16* __restrict__ Part) {
  __shared__ __align__(16) f16 sm[2 * 16384];  // 2 bufs x (A 16KB + B 16KB)

  const int tid = (int)threadIdx.x;
  const int w = tid >> 6, l = tid & 63, lo = l & 15, hi = l >> 4;
  const int wm = w >> 1, wn = w & 1;
  const int kg = tid >> 5, cg = tid & 31, ch = kg >> 2, khi = kg & 3;
  const int nb = (int)blockIdx.x, ks = (int)blockIdx.y;
  const int n0 = nb * 128;
  const int k0 = ks * 1024;

  const int r1 = tid >> 2, q = tid & 3;
  const f16* aS1 = A + (size_t)r1 * NN + k0 + 8 * (q ^ (r1 & 3));
  const f16* aS2 = A + (size_t)(64 + r1) * NN + k0 + 8 * (q ^ (r1 & 3));
  const float* Sb = S + (size_t)(k0 + 8 * kg) * NN + n0 + 4 * cg;
  f16* chunkBase = Sbt + (((size_t)ks * 64 + nb) * 32) * 4096;  // 32 chunks of 4KB

  f32x4 rgA[8], rgB[8];
  f32x4 acc[4][4] = {};

#define ISSUE_R(T, RG)                                                          \
  do {                                                                          \
    const float* s_ = Sb + (size_t)(64 * (T)) * NN;                             \
    _Pragma("unroll") for (int j_ = 0; j_ < 8; ++j_)                            \
        RG[j_] = __builtin_nontemporal_load((const f32x4*)(s_ + (size_t)j_ * NN)); \
  } while (0)

#define ISSUE_G(T)                                                              \
  do {                                                                          \
    f16* bA_ = sm + ((T)&1) * 16384;                                            \
    gload16(aS1 + 64 * (T), bA_ + tid * 8);                                     \
    gload16(aS2 + 64 * (T), bA_ + 2048 + tid * 8);                              \
    gload16(aS1 + 64 * (T) + 32, bA_ + 4096 + tid * 8);                         \
    gload16(aS2 + 64 * (T) + 32, bA_ + 4096 + 2048 + tid * 8);                  \
  } while (0)

#define CVT_W(T, RG)                                                            \
  do {                                                                          \
    f16* bB_ = sm + ((T)&1) * 16384 + 8192 + ch * 4096;                         \
    f16* g_ = chunkBase + (size_t)(2 * (T) + ch) * 4096;                        \
    _Pragma("unroll") for (int i_ = 0; i_ < 4; ++i_) {                          \
      f16x8 h_;                                                                 \
      _Pragma("unroll") for (int j_ = 0; j_ < 8; ++j_) h_[j_] = (f16)RG[j_][i_]; \
      const int c_ = 4 * cg + i_;                                               \
      const int u_ = ((c_ >> 4) << 6) + (khi << 4) + (c_ & 15);                 \
      *(f16x8*)(bB_ + (size_t)(u_ ^ (cg >> 2)) * 8) = h_;                       \
      *(f16x8*)(g_ + (size_t)u_ * 8) = h_;                                      \
    }                                                                           \
  } while (0)

  auto compute2 = [&](int par) {  // one 64-k pair = 2 chunks x 16 MFMA
    const f16* base = sm + par * 16384;
#pragma unroll
    for (int cc = 0; cc < 2; ++cc) {
      const f16* Ab = base + cc * 4096;
      const f16* Bb = base + 8192 + cc * 4096;
      f16x8 af[4], bf[4];
#pragma unroll
      for (int fm = 0; fm < 4; ++fm) {
        const int row = 64 * wm + 16 * fm + lo;
        af[fm] = *(const f16x8*)(Ab + row * 32 + 8 * (hi ^ (row & 3)));
      }
#pragma unroll
      for (int fn = 0; fn < 4; ++fn) {
        const int uu = ((wn * 4 + fn) << 6) + (hi << 4) + lo;
        bf[fn] = *(const f16x8*)(Bb + (size_t)(uu ^ (wn * 4 + fn)) * 8);
      }
      WAITL0();
      __builtin_amdgcn_sched_barrier(0);
      __builtin_amdgcn_s_setprio(1);
#pragma unroll
      for (int fm = 0; fm < 4; ++fm)
#pragma unroll
        for (int fn = 0; fn < 4; ++fn)
          acc[fm][fn] = __builtin_amdgcn_mfma_f32_16x16x32_f16(af[fm], bf[fn], acc[fm][fn], 0, 0, 0);
      __builtin_amdgcn_s_setprio(0);
    }
  };

  ISSUE_R(0, rgA);
  ISSUE_R(1, rgB);
  ISSUE_G(0);
  __builtin_amdgcn_sched_barrier(0);
  WAITV(12);
  __builtin_amdgcn_sched_barrier(0);
  CVT_W(0, rgA);
  __builtin_amdgcn_sched_barrier(0);

  for (int tt = 0; tt < 7; ++tt) {
    const int t0 = 2 * tt;
    ISSUE_R(t0 + 2, rgA);
    ISSUE_G(t0 + 1);
    __builtin_amdgcn_sched_barrier(0);
    WAITV(20);  // R8(p t0+1) done: after it G4+S4+R8+G4 = 20
    __builtin_amdgcn_sched_barrier(0);
    CVT_W(t0 + 1, rgB);
    __builtin_amdgcn_sched_barrier(0);
    WAITV(20);  // G4(p t0) done: after it S4+R8+G4+S4 = 20
    WAITL0();
    SBAR();
    compute2(0);
    SBAR();
    ISSUE_R(t0 + 3, rgB);
    ISSUE_G(t0 + 2);
    __builtin_amdgcn_sched_barrier(0);
    WAITV(20);
    __builtin_amdgcn_sched_barrier(0);
    CVT_W(t0 + 2, rgA);
    __builtin_amdgcn_sched_barrier(0);
    WAITV(20);
    WAITL0();
    SBAR();
    compute2(1);
    SBAR();
  }
  ISSUE_G(15);
  __builtin_amdgcn_sched_barrier(0);
  WAITV(12);
  __builtin_amdgcn_sched_barrier(0);
  CVT_W(15, rgB);
  __builtin_amdgcn_sched_barrier(0);
  WAITV(12);
  WAITL0();
  SBAR();
  compute2(0);
  SBAR();
  WAITV(4);
  __builtin_amdgcn_sched_barrier(0);
  SBAR();
  compute2(1);

#undef ISSUE_R
#undef ISSUE_G
#undef CVT_W

  f16* P = Part + (size_t)blockIdx.y * (GG * NN);
#pragma unroll
  for (int fm = 0; fm < 4; ++fm)
#pragma unroll
    for (int fn = 0; fn < 4; ++fn) {
      const int n = n0 + 64 * wn + 16 * fn + lo;
#pragma unroll
      for (int rr = 0; rr < 4; ++rr) {
        const int g = 64 * wm + 16 * fm + 4 * hi + rr;
        P[(size_t)g * NN + n] = (f16)acc[fm][fn][rr];
      }
    }
}

// ---------------- taps 2/3: A via LDS (proven triple-buffer), B direct-to-register ----
// B panel is read exactly once per block and the tiled Sbt layout already matches the
// MFMA fragment layout, so B skips LDS entirely: per lane one 16-B dwordx4 per fragment
// (1 KB/instr/wave, fully coalesced), 3 rotating register sets (static-indexed).
// Per iter vmem issue = 4 B-loads + 2 A-gloads = 6; steady WAITV(12) retires step t.
__global__ __launch_bounds__(256, 2) void k_tapF(const f16* __restrict__ A,
                                                 const f16* __restrict__ Bt,
                                                 f16* __restrict__ Part) {
  __shared__ __align__(16) f16 smA[3 * 4096];  // 3 x A 8KB

  const int tid = (int)threadIdx.x;
  const int w = tid >> 6, l = tid & 63, lo = l & 15, hi = l >> 4;
  const int wm = w >> 1, wn = w & 1;
  const int n0 = (int)blockIdx.x * 128;
  const int k0 = (int)blockIdx.y * 1024;  // NSPLIT=8 -> K=1024, 32 steps

  const int r1 = tid >> 2, r2 = 64 + (tid >> 2), q = tid & 3;
  const f16* aS1 = A + (size_t)r1 * NN + k0 + 8 * (q ^ (r1 & 3));
  const f16* aS2 = A + (size_t)r2 * NN + k0 + 8 * (q ^ (r2 & 3));
  const f16* bBlk = Bt + (size_t)((int)blockIdx.y * 64 + (int)blockIdx.x) * (32 * 4096);
  // per-lane B fragment pointers (step t at +t*4096)
  const f16* bK[4];
#pragma unroll
  for (int fn = 0; fn < 4; ++fn)
    bK[fn] = bBlk + ((wn * 4 + fn) << 9) + hi * 128 + lo * 8;

  f32x4 acc[4][4] = {};
  f16x8 bf0[4], bf1[4], bf2[4];

#define ISSUE_A(T, OFF)                                             \
  do {                                                              \
    f16* b_ = smA + (OFF) * 4096;                                   \
    gload16(aS1 + (T) * 32, b_ + tid * 8);                          \
    gload16(aS2 + (T) * 32, b_ + 2048 + tid * 8);                   \
  } while (0)

#define ISSUE_B(T, BF)                                              \
  do {                                                              \
    _Pragma("unroll") for (int fn_ = 0; fn_ < 4; ++fn_)             \
        BF[fn_] = *(const f16x8*)(bK[fn_] + (size_t)(T) * 4096);    \
  } while (0)

#define COMPUTE(OFF, BF)                                                          \
  do {                                                                            \
    const f16* Ab = smA + (OFF) * 4096;                                           \
    f16x8 af_[4];                                                                 \
    _Pragma("unroll") for (int fm_ = 0; fm_ < 4; ++fm_) {                         \
      const int row_ = 64 * wm + 16 * fm_ + lo;                                   \
      af_[fm_] = *(const f16x8*)(Ab + row_ * 32 + 8 * (hi ^ (row_ & 3)));         \
    }                                                                             \
    WAITL0();                                                                     \
    __builtin_amdgcn_sched_barrier(0);                                            \
    __builtin_amdgcn_s_setprio(1);                                                \
    _Pragma("unroll") for (int fm_ = 0; fm_ < 4; ++fm_)                           \
      _Pragma("unroll") for (int fn_ = 0; fn_ < 4; ++fn_)                         \
        acc[fm_][fn_] =                                                           \
            __builtin_amdgcn_mfma_f32_16x16x32_f16(af_[fm_], BF[fn_], acc[fm_][fn_], 0, 0, 0); \
    __builtin_amdgcn_s_setprio(0);                                                \
  } while (0)

#define BODY(T, OFFC, OFFN, BFC, BFN)       \
  do {                                      \
    ISSUE_B((T) + 2, BFN);                  \
    ISSUE_A((T) + 2, OFFN);                 \
    __builtin_amdgcn_sched_barrier(0);      \
    WAITV(12);                              \
    SBAR();                                 \
    COMPUTE(OFFC, BFC);                     \
    SBAR();                                 \
  } while (0)

  // prologue: B0,A0,B1,A1 -> 12 outstanding
  ISSUE_B(0, bf0);
  ISSUE_A(0, 0);
  ISSUE_B(1, bf1);
  ISSUE_A(1, 1);
  __builtin_amdgcn_sched_barrier(0);

  for (int tt = 0; tt < 10; ++tt) {
    const int t0 = 3 * tt;
    BODY(t0 + 0, 0, 2, bf0, bf2);
    BODY(t0 + 1, 1, 0, bf1, bf0);
    BODY(t0 + 2, 2, 1, bf2, bf1);
  }
  // tail: T=30 (buf0, bf0): outstanding = B30 A30 B31 A31 = 12 -> retire 30 via WAITV(6)
  WAITV(6);
  SBAR();
  COMPUTE(0, bf0);
  SBAR();
  // T=31 (buf1, bf1)
  WAITV(0);
  SBAR();
  COMPUTE(1, bf1);

#undef ISSUE_A
#undef ISSUE_B
#undef COMPUTE
#undef BODY

  f16* P = Part + (size_t)blockIdx.y * (GG * NN);
#pragma unroll
  for (int fm = 0; fm < 4; ++fm)
#pragma unroll
    for (int fn = 0; fn < 4; ++fn) {
      const int n = n0 + 64 * wn + 16 * fn + lo;
#pragma unroll
      for (int rr = 0; rr < 4; ++rr) {
        const int g = 64 * wm + 16 * fm + 4 * hi + rr;
        P[(size_t)g * NN + n] = (f16)acc[fm][fn][rr];
      }
    }
}

// ---------------- combine: vectorized 16-B loads, 8 elems/thread ----------------
template <int FINAL>
__global__ void k_combine(const f16* __restrict__ Part, const f16* __restrict__ wz,
                          const float* __restrict__ bias, f16* __restrict__ tn,
                          float* __restrict__ y) {
  const int idx = (int)blockIdx.x * 512 + (int)threadIdx.x;  // 8 elems each
  const size_t off = (size_t)idx * 8;
  f16x8 wv = *(const f16x8*)(wz + off);
  float s[8];
#pragma unroll
  for (int j = 0; j < 8; ++j) s[j] = (float)wv[j];
#pragma unroll
  for (int sp = 0; sp < NSPLIT; ++sp) {
    f16x8 p = __builtin_nontemporal_load((const f16x8*)(Part + (size_t)sp * (GG * NN) + off));
#pragma unroll
    for (int j = 0; j < 8; ++j) s[j] += (float)p[j];
  }
  if (FINAL) {
    const float b = bias[(int)(off >> 13)];
    f32x4 o0, o1;
#pragma unroll
    for (int j = 0; j < 4; ++j) { o0[j] = s[j] + b; o1[j] = s[4 + j] + b; }
    __builtin_nontemporal_store(o0, (f32x4*)(y + off));
    __builtin_nontemporal_store(o1, (f32x4*)(y + off + 4));
  } else {
    f16x8 o;
#pragma unroll
    for (int j = 0; j < 8; ++j) o[j] = (f16)s[j];
    *(f16x8*)(tn + off) = o;
  }
}

extern "C" void kernel_launch(void* const* d_in, const int* in_sizes, int n_in, void* d_out,
                              int out_size, void* d_ws, size_t ws_size, hipStream_t stream) {
  const float* x = (const float*)d_in[0];   // [8192][128]
  const float* S = (const float*)d_in[1];   // [8192][8192] fp32
  const float* wt = (const float*)d_in[2];  // [128][1][4][128]
  const float* bs = (const float*)d_in[3];  // [128]
  float* y = (float*)d_out;                 // [128][8192] fp32
  char* ws = (char*)d_ws;

  const size_t offSbt = 0;                               // Sbt tiled f16: 134.2 MB
  const size_t offWz = offSbt + (size_t)NN * NN * 2;     // wz[4][128][8192] f16: 8 MB
  const size_t offTa = offWz + (size_t)4 * GG * NN * 2;  // t buf A: 2 MB
  const size_t offTb = offTa + (size_t)GG * NN * 2;      // t buf B: 2 MB
  const size_t offP = offTb + (size_t)GG * NN * 2;       // Part f16 [8][128][8192]: 16.8 MB
  const size_t need = offP + (size_t)NSPLIT * GG * NN * 2;
  if (ws_size < need) return;

  f16* Sbt = (f16*)(ws + offSbt);
  f16* wz = (f16*)(ws + offWz);
  f16* ta = (f16*)(ws + offTa);
  f16* tb = (f16*)(ws + offTb);
  f16* Part = (f16*)(ws + offP);

  // wz first (tap1 consumes wz3), then fused stream+tap1, then Horner chain.
  k_wz<<<dim3(256, 4), 512, 0, stream>>>(wt, x, wz);
  k_tap1F<<<dim3(64, NSPLIT), 256, 0, stream>>>(wz + (size_t)3 * GG * NN, S, Sbt, Part);
  k_combine<0><<<dim3(256), 512, 0, stream>>>(Part, wz + (size_t)2 * GG * NN, nullptr, ta, nullptr);
  k_tapF<<<dim3(64, NSPLIT), 256, 0, stream>>>(ta, Sbt, Part);
  k_combine<0><<<dim3(256), 512, 0, stream>>>(Part, wz + (size_t)1 * GG * NN, nullptr, tb, nullptr);
  k_tapF<<<dim3(64, NSPLIT), 256, 0, stream>>>(tb, Sbt, Part);
  k_combine<1><<<dim3(256), 512, 0, stream>>>(Part, wz, bs, nullptr, y);
}